// Round 8
// baseline (161.244 us; speedup 1.0000x reference)
//
#include <hip/hip_runtime.h>

// CINLayer: cin_out[b,f,d] = sum_{c,n} W[f,c,n] * xj[b,c,d] * x0[b,n,d]
//           cin_p_out[b,f] = sum_d cin_out[b,f,d]
// B=2048, C=64, N=64, D=64, F=128.
//
// R8: occupancy round. Wave = 1 batch x 32 f (af 32V + acc 32A + W 32V
// ~= 124 regs -> 4 waves/SIMD via __launch_bounds__(512,4)). 8-wave blocks,
// 2 batches/block, grid 1024 = 4 blocks/CU over 2 resident = 2 clean rounds,
// no tail. Same fragment-major W reg-stream + xj-LDS structure as R6/R7.

typedef _Float16 f16;
typedef __attribute__((ext_vector_type(8))) _Float16 half8;
typedef __attribute__((ext_vector_type(4))) _Float16 half4;
typedef __attribute__((ext_vector_type(2))) _Float16 half2v;
typedef __attribute__((ext_vector_type(16))) float f32x16;
typedef __attribute__((ext_vector_type(4))) float f32x4;

#define MFMA(a, b, c) __builtin_amdgcn_mfma_f32_32x32x16_f16(a, b, c, 0, 0, 0)

union H8 { half8 v; half2v h[4]; };

__device__ __forceinline__ half8 scale8(half8 a, half2v hh) {
  H8 in, out;
  in.v = a;
  out.h[0] = in.h[0] * hh;
  out.h[1] = in.h[1] * hh;
  out.h[2] = in.h[2] * hh;
  out.h[3] = in.h[3] * hh;
  return out.v;
}

// ---- pre-pass: scatter W f32 -> f16 fragment-major ----
// Wb slot layout: [c][slot][8], slot = (g*4+kk)*64 + hi*32 + lr
//   holds W[f=g*32+lr][c][kk*16+hi*8 .. +8]
__global__ __launch_bounds__(256) void wscat_kernel(const float* __restrict__ W,
                                                    f16* __restrict__ Wb) {
  const int tid = blockIdx.x * 256 + threadIdx.x;   // 65536 threads
  const int c = tid >> 10, s = tid & 1023;
  const int gk = s >> 6, ln = s & 63;
  const int g = gk >> 2, kk = gk & 3, hi = ln >> 5, lr = ln & 31;
  const int f = g * 32 + lr, n0 = kk * 16 + hi * 8;
  const float* src = W + (size_t)f * 4096 + c * 64 + n0;
  const float4 a = *(const float4*)src;
  const float4 b = *(const float4*)(src + 4);
  half8 r;
  r[0] = (f16)a.x; r[1] = (f16)a.y; r[2] = (f16)a.z; r[3] = (f16)a.w;
  r[4] = (f16)b.x; r[5] = (f16)b.y; r[6] = (f16)b.z; r[7] = (f16)b.w;
  *(half8*)(Wb + (size_t)c * 8192 + s * 8) = r;
}

__global__ __launch_bounds__(512, 4) void cin_kernel(
    const float* __restrict__ xj, const float* __restrict__ x0,
    const f16* __restrict__ Wb, float* __restrict__ out,
    float* __restrict__ pout) {
  // x0T[bb*4096 + d*64 + ((n>>3)^(d&7))*8 + (n&7)] = f16(x0[b0+bb][n][d])
  __shared__ f16 x0T[2 * 4096];   // 16 KB
  // xjL[bb*4096 + c*64 + d] = f16(xj[b0+bb][c][d])   (linear copy)
  __shared__ f16 xjL[2 * 4096];   // 16 KB

  const int t = threadIdx.x;
  const int b0 = blockIdx.x * 2;

  // ---- one-time staging: half-block per batch ----
  {
    const int sel = t >> 8, th = t & 255;        // sel = batch
    const int wid8 = th >> 6, lane8 = th & 63;
    const float* s0 = x0 + (size_t)(b0 + sel) * 4096;
    const float* sj = xj + (size_t)(b0 + sel) * 4096;
    // x0: transpose + swizzle; thread reads row n=lane8, d-chunk wid8*16
    {
      const int n = lane8, d0 = wid8 * 16;
      const int chb = n >> 3, sub = n & 7;
#pragma unroll
      for (int q = 0; q < 4; ++q) {
        const float4 v = *(const float4*)(s0 + n * 64 + d0 + q * 4);
#pragma unroll
        for (int j = 0; j < 4; ++j) {
          const int d = d0 + q * 4 + j;
          x0T[sel * 4096 + d * 64 + ((chb ^ (d & 7)) << 3) + sub] =
              (f16)(((const float*)&v)[j]);
        }
      }
    }
    // xj: linear f16 copy, 8B LDS writes
#pragma unroll
    for (int p = 0; p < 4; ++p) {
      const int e = p * 1024 + th * 4;
      const float4 v = *(const float4*)(sj + e);
      half4 r; r[0] = (f16)v.x; r[1] = (f16)v.y; r[2] = (f16)v.z; r[3] = (f16)v.w;
      *(half4*)&xjL[sel * 4096 + e] = r;
    }
  }
  __syncthreads();

  const int wid = t >> 6, lane = t & 63;
  const int bb = wid >> 2, wg = wid & 3;    // wave: batch bb, f-group wg
  const int lr = lane & 31, hi = lane >> 5;

  // ---- hoisted x0 A-fragments: af[dh][kk], d = dh*32 + lr ----
  half8 af[2][4];
#pragma unroll
  for (int dh = 0; dh < 2; ++dh) {
    const int d = dh * 32 + lr;
#pragma unroll
    for (int kk = 0; kk < 4; ++kk)
      af[dh][kk] = *(const half8*)&x0T[bb * 4096 + d * 64 +
                                       (((kk * 2 + hi) ^ (d & 7)) << 3)];
  }

  f32x16 acc[2] = {};

  // W stream: wave wg's slice, 16B/lane contiguous per (c,kk)
  const half8* wp = (const half8*)Wb + wg * 256 + lane;   // + c*1024 + kk*64
  const f16* xjA = &xjL[bb * 4096 + lr];   // even c
  const f16* xjB = xjA + 64;               // odd c

  // ---- prologue: c=0 -> A sets, c=1 -> B sets ----
  half8 wA0 = wp[0],    wA1 = wp[64],        wA2 = wp[128],        wA3 = wp[192];
  half8 wB0 = wp[1024], wB1 = wp[1024 + 64], wB2 = wp[1024 + 128], wB3 = wp[1024 + 192];
  f16 xA0 = xjA[0], xA1 = xjA[32];
  f16 xB0 = xjB[0], xB1 = xjB[32];

  // moving prefetch pointers (next targets: c=2 / c=3)
  const half8* wpA = wp + 2048;
  const half8* wpB = wp + 3072;
  const f16* xjpA = xjA + 128;
  const f16* xjpB = xjB + 128;

#pragma unroll 1
  for (int cc = 0; cc < 32; ++cc) {
    // ================= even c = 2*cc (A sets) =================
    {
      const half2v h0 = {xA0, xA0}, h1 = {xA1, xA1};
      __builtin_amdgcn_s_setprio(1);
#pragma unroll
      for (int kk = 0; kk < 4; ++kk) {
        const half8 w = (kk == 0) ? wA0 : (kk == 1) ? wA1 : (kk == 2) ? wA2 : wA3;
        acc[0] = MFMA(scale8(af[0][kk], h0), w, acc[0]);
        acc[1] = MFMA(scale8(af[1][kk], h1), w, acc[1]);
      }
      __builtin_amdgcn_s_setprio(0);
      if (cc < 31) {
        wA0 = wpA[0]; wA1 = wpA[64]; wA2 = wpA[128]; wA3 = wpA[192];
        xA0 = xjpA[0]; xA1 = xjpA[32];
        wpA += 2048; xjpA += 128;
      }
    }
    // ================= odd c = 2*cc+1 (B sets) =================
    {
      const half2v h0 = {xB0, xB0}, h1 = {xB1, xB1};
      __builtin_amdgcn_s_setprio(1);
#pragma unroll
      for (int kk = 0; kk < 4; ++kk) {
        const half8 w = (kk == 0) ? wB0 : (kk == 1) ? wB1 : (kk == 2) ? wB2 : wB3;
        acc[0] = MFMA(scale8(af[0][kk], h0), w, acc[0]);
        acc[1] = MFMA(scale8(af[1][kk], h1), w, acc[1]);
      }
      __builtin_amdgcn_s_setprio(0);
      if (cc < 31) {
        wB0 = wpB[0]; wB1 = wpB[64]; wB2 = wpB[128]; wB3 = wpB[192];
        xB0 = xjpB[0]; xB1 = xjpB[32];
        wpB += 2048; xjpB += 128;
      }
    }
  }

  // ---- epilogue: D layout col=lane&31 (f), row=(reg&3)+8*(reg>>2)+4*hi (d) ----
  const int fcol = wg * 32 + lr;
  const int b = b0 + bb;
  float* ob = out + (size_t)b * 8192 + (size_t)fcol * 64;
  float psum = 0.f;
#pragma unroll
  for (int dh = 0; dh < 2; ++dh) {
    const f32x16 v = acc[dh];
#pragma unroll
    for (int q = 0; q < 4; ++q) {
      f32x4 vv = { v[4 * q], v[4 * q + 1], v[4 * q + 2], v[4 * q + 3] };
      *(f32x4*)(ob + dh * 32 + q * 8 + hi * 4) = vv;
      psum += vv[0] + vv[1] + vv[2] + vv[3];
    }
  }
  psum += __shfl_xor(psum, 32, 64);
  if (hi == 0) pout[(size_t)b * 128 + fcol] = psum;
}

extern "C" void kernel_launch(void* const* d_in, const int* in_sizes, int n_in,
                              void* d_out, int out_size, void* d_ws, size_t ws_size,
                              hipStream_t stream) {
  const float* xj = (const float*)d_in[0];   // (2048, 64, 64)
  const float* x0 = (const float*)d_in[1];   // (2048, 64, 64)
  const float* W  = (const float*)d_in[2];   // (128, 64, 64)
  float* out  = (float*)d_out;               // cin_out (2048,128,64), cin_p_out (2048,128)
  float* pout = out + (size_t)2048 * 128 * 64;
  f16* Wb = (f16*)d_ws;                      // 1 MiB fragment-major f16 W

  wscat_kernel<<<256, 256, 0, stream>>>(W, Wb);
  cin_kernel<<<1024, 512, 0, stream>>>(xj, x0, Wb, out, pout);
}

// Round 9
// 148.021 us; speedup vs baseline: 1.0893x; 1.0893x over previous
//
#include <hip/hip_runtime.h>

// CINLayer: cin_out[b,f,d] = sum_{c,n} W[f,c,n] * xj[b,c,d] * x0[b,n,d]
//           cin_p_out[b,f] = sum_d cin_out[b,f,d]
// B=2048, C=64, N=64, D=64, F=128.
//
// R9: R7 wave shape (2 batches x 32 f, 16 MFMA/c) + W via LDS 3-buffer
// counted-vmcnt pipeline (stage-distance 3, vmcnt(4) at barriers, never
// drained) + 64KB LDS -> 2 blocks/CU cover each other's barrier stalls +
// grid 1024 = 2 exact residency rounds (no tail). x0T borrows buf2's LDS
// during the prologue. xj packed [c][d][bb] in LDS, ds_read_b32 per phase.

typedef _Float16 f16;
typedef __attribute__((ext_vector_type(8))) _Float16 half8;
typedef __attribute__((ext_vector_type(2))) _Float16 half2v;
typedef __attribute__((ext_vector_type(16))) float f32x16;
typedef __attribute__((ext_vector_type(4))) float f32x4;

#define MFMA(a, b, c) __builtin_amdgcn_mfma_f32_32x32x16_f16(a, b, c, 0, 0, 0)

#define GLOAD16(g, l) __builtin_amdgcn_global_load_lds( \
    (const __attribute__((address_space(1))) void*)(g), \
    (__attribute__((address_space(3))) void*)(l), 16, 0, 0)

union H8 { half8 v; half2v h[4]; };

__device__ __forceinline__ half8 scale8(half8 a, half2v hh) {
  H8 in, out;
  in.v = a;
  out.h[0] = in.h[0] * hh;
  out.h[1] = in.h[1] * hh;
  out.h[2] = in.h[2] * hh;
  out.h[3] = in.h[3] * hh;
  return out.v;
}

// ---- pre-pass: scatter W f32 -> f16 fragment-major ----
// Wb slot layout: [c][slot][8], slot = (g*4+kk)*64 + hi*32 + lr
//   holds W[f=g*32+lr][c][kk*16+hi*8 .. +8]
__global__ __launch_bounds__(256) void wscat_kernel(const float* __restrict__ W,
                                                    f16* __restrict__ Wb) {
  const int tid = blockIdx.x * 256 + threadIdx.x;   // 65536 threads
  const int c = tid >> 10, s = tid & 1023;
  const int gk = s >> 6, ln = s & 63;
  const int g = gk >> 2, kk = gk & 3, hi = ln >> 5, lr = ln & 31;
  const int f = g * 32 + lr, n0 = kk * 16 + hi * 8;
  const float* src = W + (size_t)f * 4096 + c * 64 + n0;
  const float4 a = *(const float4*)src;
  const float4 b = *(const float4*)(src + 4);
  half8 r;
  r[0] = (f16)a.x; r[1] = (f16)a.y; r[2] = (f16)a.z; r[3] = (f16)a.w;
  r[4] = (f16)b.x; r[5] = (f16)b.y; r[6] = (f16)b.z; r[7] = (f16)b.w;
  *(half8*)(Wb + (size_t)c * 8192 + s * 8) = r;
}

// S layout (f16 elems): [0..24575] Wt 3 bufs x 8192 ; prologue x0T at 16384
// (buf2's space, dead before c=2 is staged); [24576..32767] xjP[c][d][bb].
#define X0T 16384
#define XJ0 24576

#define PHASE(CEXPR, BUF, CUR, NXT) do {                                       \
  const int c_ = (CEXPR);                                                      \
  { const int cs_ = (c_ + 3 <= 63) ? (c_ + 3) : 63;                            \
    const f16* gs_ = Wb + (size_t)cs_ * 8192;                                  \
    _Pragma("unroll")                                                          \
    for (int p = 0; p < 4; ++p)                                                \
      GLOAD16(gs_ + (p * 256 + t) * 8,                                         \
              &S[BUF * 8192 + (p * 256 + (wid << 6)) * 8]); }                  \
  { const int cn_ = (c_ + 1 <= 63) ? (c_ + 1) : 63;                            \
    const f16* ws_ = &S[((BUF + 1) % 3) * 8192 + wg * 2048 + lane * 8];        \
    w##NXT##0 = *(const half8*)(ws_ + 0 * 512);                                \
    w##NXT##1 = *(const half8*)(ws_ + 1 * 512);                                \
    w##NXT##2 = *(const half8*)(ws_ + 2 * 512);                                \
    w##NXT##3 = *(const half8*)(ws_ + 3 * 512);                                \
    xj##NXT##0 = *(const half2v*)&S[XJ0 + cn_ * 128 + lr * 2];                 \
    xj##NXT##1 = *(const half2v*)&S[XJ0 + cn_ * 128 + (32 + lr) * 2]; }        \
  { const half2v h0 = {xj##CUR##0[0], xj##CUR##0[0]};                          \
    const half2v h1 = {xj##CUR##1[0], xj##CUR##1[0]};                          \
    const half2v h2 = {xj##CUR##0[1], xj##CUR##0[1]};                          \
    const half2v h3 = {xj##CUR##1[1], xj##CUR##1[1]};                          \
    __builtin_amdgcn_s_setprio(1);                                             \
    _Pragma("unroll")                                                          \
    for (int kk = 0; kk < 4; ++kk) {                                           \
      const half8 wv = (kk == 0) ? w##CUR##0 : (kk == 1) ? w##CUR##1 :         \
                       (kk == 2) ? w##CUR##2 : w##CUR##3;                      \
      acc[0] = MFMA(scale8(af[0][kk], h0), wv, acc[0]);                        \
      acc[1] = MFMA(scale8(af[1][kk], h1), wv, acc[1]);                        \
      acc[2] = MFMA(scale8(af[2][kk], h2), wv, acc[2]);                        \
      acc[3] = MFMA(scale8(af[3][kk], h3), wv, acc[3]); }                      \
    __builtin_amdgcn_s_setprio(0); }                                           \
  asm volatile("s_waitcnt vmcnt(4) lgkmcnt(0)" ::: "memory");                  \
  __builtin_amdgcn_s_barrier();                                                \
  __builtin_amdgcn_sched_barrier(0);                                           \
} while (0)

__global__ __launch_bounds__(256, 2) void cin_kernel(
    const float* __restrict__ xj, const float* __restrict__ x0,
    const f16* __restrict__ Wb, float* __restrict__ out,
    float* __restrict__ pout) {
  __shared__ f16 S[32768];   // 64 KB -> 2 blocks/CU

  const int t = threadIdx.x;
  const int wid = t >> 6, lane = t & 63;
  const int b0 = blockIdx.x * 2;
  const int wg = wid;                       // f-group: f = wg*32 + lr
  const int lr = lane & 31, hi = lane >> 5;

  // ---- prologue 1: stage x0T (transposed+swizzled, into buf2 space) + xjP ----
#pragma unroll
  for (int bb = 0; bb < 2; ++bb) {
    const float* s0 = x0 + (size_t)(b0 + bb) * 4096;
    const int n = lane, d0 = wid * 16;
    const int chb = n >> 3, sub = n & 7;
#pragma unroll
    for (int q = 0; q < 4; ++q) {
      const float4 v = *(const float4*)(s0 + n * 64 + d0 + q * 4);
#pragma unroll
      for (int j = 0; j < 4; ++j) {
        const int d = d0 + q * 4 + j;
        S[X0T + bb * 4096 + d * 64 + ((chb ^ (d & 7)) << 3) + sub] =
            (f16)(((const float*)&v)[j]);
      }
    }
  }
  {  // xjP[c][d][bb]: thread handles (bb, c, 32-d half)
    const int bb = t >> 7, r = t & 127, cr = r >> 1, dn = (r & 1) * 32;
    const float* sj = xj + (size_t)(b0 + bb) * 4096 + cr * 64 + dn;
#pragma unroll
    for (int q = 0; q < 8; ++q) {
      const float4 v = *(const float4*)(sj + q * 4);
#pragma unroll
      for (int j = 0; j < 4; ++j)
        S[XJ0 + cr * 128 + (dn + q * 4 + j) * 2 + bb] =
            (f16)(((const float*)&v)[j]);
    }
  }
  __syncthreads();

  // ---- prologue 2: stage W(0)->buf0, W(1)->buf1 (x0T in buf2 still live) ----
#pragma unroll
  for (int cc = 0; cc < 2; ++cc)
#pragma unroll
    for (int p = 0; p < 4; ++p)
      GLOAD16(Wb + (size_t)cc * 8192 + (p * 256 + t) * 8,
              &S[cc * 8192 + (p * 256 + (wid << 6)) * 8]);

  // ---- hoist x0 A-fragments from x0T: af[mf][kk], mf = (bb<<1)|dh ----
  half8 af[4][4];
#pragma unroll
  for (int mf = 0; mf < 4; ++mf) {
    const int bb = mf >> 1;
    const int d = (mf & 1) * 32 + lr;
#pragma unroll
    for (int kk = 0; kk < 4; ++kk)
      af[mf][kk] = *(const half8*)&S[X0T + bb * 4096 + d * 64 +
                                     (((kk * 2 + hi) ^ (d & 7)) << 3)];
  }
  half2v xjA0 = *(const half2v*)&S[XJ0 + lr * 2];
  half2v xjA1 = *(const half2v*)&S[XJ0 + (32 + lr) * 2];
  half2v xjB0, xjB1;

  // buf0 landed (8 outstanding -> <=4 leaves only buf1); af reads drained
  asm volatile("s_waitcnt vmcnt(4) lgkmcnt(0)" ::: "memory");
  __builtin_amdgcn_s_barrier();

  // ---- stage W(2)->buf2 (x0T dead now) ----
#pragma unroll
  for (int p = 0; p < 4; ++p)
    GLOAD16(Wb + (size_t)2 * 8192 + (p * 256 + t) * 8,
            &S[2 * 8192 + (p * 256 + (wid << 6)) * 8]);

  // ---- read W(0) -> A set ----
  half8 wA0, wA1, wA2, wA3, wB0, wB1, wB2, wB3;
  {
    const f16* ws = &S[wg * 2048 + lane * 8];
    wA0 = *(const half8*)(ws + 0 * 512);
    wA1 = *(const half8*)(ws + 1 * 512);
    wA2 = *(const half8*)(ws + 2 * 512);
    wA3 = *(const half8*)(ws + 3 * 512);
  }
  // buf1 guaranteed landed for phase0's read of W(1); W(0) reads drained
  asm volatile("s_waitcnt vmcnt(4) lgkmcnt(0)" ::: "memory");
  __builtin_amdgcn_s_barrier();
  __builtin_amdgcn_sched_barrier(0);

  f32x16 acc[4] = {};

  // ---- main loop: phases c = 0..62 (6-phase unroll), tail c = 63 ----
#pragma unroll 1
  for (int i = 0; i < 10; ++i) {
    const int cb = 6 * i;
    PHASE(cb + 0, 0, A, B);
    PHASE(cb + 1, 1, B, A);
    PHASE(cb + 2, 2, A, B);
    PHASE(cb + 3, 0, B, A);
    PHASE(cb + 4, 1, A, B);
    PHASE(cb + 5, 2, B, A);
  }
  PHASE(60, 0, A, B);
  PHASE(61, 1, B, A);
  PHASE(62, 2, A, B);
  {  // tail c=63: MFMA only on B set
    const half2v h0 = {xjB0[0], xjB0[0]};
    const half2v h1 = {xjB1[0], xjB1[0]};
    const half2v h2 = {xjB0[1], xjB0[1]};
    const half2v h3 = {xjB1[1], xjB1[1]};
    __builtin_amdgcn_s_setprio(1);
#pragma unroll
    for (int kk = 0; kk < 4; ++kk) {
      const half8 wv = (kk == 0) ? wB0 : (kk == 1) ? wB1 : (kk == 2) ? wB2 : wB3;
      acc[0] = MFMA(scale8(af[0][kk], h0), wv, acc[0]);
      acc[1] = MFMA(scale8(af[1][kk], h1), wv, acc[1]);
      acc[2] = MFMA(scale8(af[2][kk], h2), wv, acc[2]);
      acc[3] = MFMA(scale8(af[3][kk], h3), wv, acc[3]);
    }
    __builtin_amdgcn_s_setprio(0);
  }

  // ---- epilogue: D layout col=lane&31 (f), row=(reg&3)+8*(reg>>2)+4*hi (d) ----
  const int fcol = wg * 32 + lr;
  float ps[4];
#pragma unroll
  for (int mf = 0; mf < 4; ++mf) {
    const int b = b0 + (mf >> 1);
    float* ob = out + (size_t)b * 8192 + (size_t)fcol * 64 + (mf & 1) * 32;
    const f32x16 v = acc[mf];
    float s = 0.f;
#pragma unroll
    for (int q = 0; q < 4; ++q) {
      f32x4 vv = { v[4 * q], v[4 * q + 1], v[4 * q + 2], v[4 * q + 3] };
      *(f32x4*)(ob + q * 8 + hi * 4) = vv;
      s += vv[0] + vv[1] + vv[2] + vv[3];
    }
    ps[mf] = s;
  }
  float pA = ps[0] + ps[1];   // batch b0
  float pB = ps[2] + ps[3];   // batch b0+1
  pA += __shfl_xor(pA, 32, 64);
  pB += __shfl_xor(pB, 32, 64);
  if (hi == 0) {
    pout[(size_t)b0 * 128 + fcol] = pA;
    pout[(size_t)(b0 + 1) * 128 + fcol] = pB;
  }
}

extern "C" void kernel_launch(void* const* d_in, const int* in_sizes, int n_in,
                              void* d_out, int out_size, void* d_ws, size_t ws_size,
                              hipStream_t stream) {
  const float* xj = (const float*)d_in[0];   // (2048, 64, 64)
  const float* x0 = (const float*)d_in[1];   // (2048, 64, 64)
  const float* W  = (const float*)d_in[2];   // (128, 64, 64)
  float* out  = (float*)d_out;               // cin_out (2048,128,64), cin_p_out (2048,128)
  float* pout = out + (size_t)2048 * 128 * 64;
  f16* Wb = (f16*)d_ws;                      // 1 MiB fragment-major f16 W

  wscat_kernel<<<256, 256, 0, stream>>>(W, Wb);
  cin_kernel<<<1024, 256, 0, stream>>>(xj, x0, Wb, out, pout);
}

// Round 10
// 141.369 us; speedup vs baseline: 1.1406x; 1.0471x over previous
//
#include <hip/hip_runtime.h>

// CINLayer: cin_out[b,f,d] = sum_{c,n} W[f,c,n] * xj[b,c,d] * x0[b,n,d]
//           cin_p_out[b,f] = sum_d cin_out[b,f,d]
// B=2048, C=64, N=64, D=64, F=128.
//
// R10 = R7 + persistent blocks: grid 512 (2 blocks/CU resident, constant),
// each block processes 2 batch-pairs sequentially. Eliminates R7's hidden
// 3-resident/4-work mismatch (40% of wall ran 1 block/CU -> util ~35%).
// Everything else identical to R7 (best so far, 139.7us).

typedef _Float16 f16;
typedef __attribute__((ext_vector_type(8))) _Float16 half8;
typedef __attribute__((ext_vector_type(4))) _Float16 half4;
typedef __attribute__((ext_vector_type(2))) _Float16 half2v;
typedef __attribute__((ext_vector_type(16))) float f32x16;
typedef __attribute__((ext_vector_type(4))) float f32x4;

#define MFMA(a, b, c) __builtin_amdgcn_mfma_f32_32x32x16_f16(a, b, c, 0, 0, 0)

union H8 { half8 v; half2v h[4]; };

__device__ __forceinline__ half8 scale8(half8 a, half2v hh) {
  H8 in, out;
  in.v = a;
  out.h[0] = in.h[0] * hh;
  out.h[1] = in.h[1] * hh;
  out.h[2] = in.h[2] * hh;
  out.h[3] = in.h[3] * hh;
  return out.v;
}

// ---- pre-pass: scatter W f32 -> f16 fragment-major ----
// Wb slot layout: [c][slot][8], slot = (g*4+kk)*64 + hi*32 + lr
//   holds W[f=g*32+lr][c][kk*16+hi*8 .. +8]
__global__ __launch_bounds__(256) void wscat_kernel(const float* __restrict__ W,
                                                    f16* __restrict__ Wb) {
  const int tid = blockIdx.x * 256 + threadIdx.x;   // 65536 threads
  const int c = tid >> 10, s = tid & 1023;
  const int gk = s >> 6, ln = s & 63;
  const int g = gk >> 2, kk = gk & 3, hi = ln >> 5, lr = ln & 31;
  const int f = g * 32 + lr, n0 = kk * 16 + hi * 8;
  const float* src = W + (size_t)f * 4096 + c * 64 + n0;
  const float4 a = *(const float4*)src;
  const float4 b = *(const float4*)(src + 4);
  half8 r;
  r[0] = (f16)a.x; r[1] = (f16)a.y; r[2] = (f16)a.z; r[3] = (f16)a.w;
  r[4] = (f16)b.x; r[5] = (f16)b.y; r[6] = (f16)b.z; r[7] = (f16)b.w;
  *(half8*)(Wb + (size_t)c * 8192 + s * 8) = r;
}

__global__ __launch_bounds__(256, 2) void cin_kernel(
    const float* __restrict__ xj, const float* __restrict__ x0,
    const f16* __restrict__ Wb, float* __restrict__ out,
    float* __restrict__ pout) {
  // x0T[bb*4096 + d*64 + ((n>>3)^(d&7))*8 + (n&7)] = f16(x0[b0+bb][n][d])
  __shared__ f16 x0T[2 * 4096];   // 16 KB
  // xjL[bb*4096 + c*64 + d] = f16(xj[b0+bb][c][d])   (linear copy)
  __shared__ f16 xjL[2 * 4096];   // 16 KB

  const int t = threadIdx.x;
  const int wid = t >> 6, lane = t & 63;
  const int wg = wid;                       // f-group: f = wg*32 + lr
  const int lr = lane & 31, hi = lane >> 5;

#pragma unroll 1
  for (int pr = 0; pr < 2; ++pr) {
    const int b0 = (blockIdx.x + pr * 512) * 2;
    if (pr) __syncthreads();   // prior pair's xjL/x0T reads complete

    // ---- one-time per pair: stage x0 (transposed, swizzled) + xj (linear) ----
#pragma unroll
    for (int bb = 0; bb < 2; ++bb) {
      const float* s0 = x0 + (size_t)(b0 + bb) * 4096;
      const float* sj = xj + (size_t)(b0 + bb) * 4096;
      {
        const int n = lane, d0 = wid * 16;
        const int chb = n >> 3, sub = n & 7;
#pragma unroll
        for (int q = 0; q < 4; ++q) {
          const float4 v = *(const float4*)(s0 + n * 64 + d0 + q * 4);
#pragma unroll
          for (int j = 0; j < 4; ++j) {
            const int d = d0 + q * 4 + j;
            x0T[bb * 4096 + d * 64 + ((chb ^ (d & 7)) << 3) + sub] =
                (f16)(((const float*)&v)[j]);
          }
        }
      }
#pragma unroll
      for (int p = 0; p < 4; ++p) {
        const int e = p * 1024 + t * 4;
        const float4 v = *(const float4*)(sj + e);
        half4 r; r[0] = (f16)v.x; r[1] = (f16)v.y; r[2] = (f16)v.z; r[3] = (f16)v.w;
        *(half4*)&xjL[bb * 4096 + e] = r;
      }
    }
    __syncthreads();

    // ---- hoisted x0 A-fragments: af[mf][kk], mf = (bb<<1)|dh ----
    half8 af[4][4];
#pragma unroll
    for (int mf = 0; mf < 4; ++mf) {
      const int bb = mf >> 1;
      const int d = (mf & 1) * 32 + lr;
#pragma unroll
      for (int kk = 0; kk < 4; ++kk)
        af[mf][kk] = *(const half8*)&x0T[bb * 4096 + d * 64 +
                                         (((kk * 2 + hi) ^ (d & 7)) << 3)];
    }

    f32x16 acc[4] = {};

    // W stream: wave wg's slice, 16B/lane contiguous per (c,kk)
    const half8* wp = (const half8*)Wb + wg * 256 + lane;   // + c*1024 + kk*64
    const f16* xjA = &xjL[lr];          // even c
    const f16* xjB = &xjL[lr] + 64;     // odd c

    // ---- prologue: c=0 -> A sets, c=1 -> B sets ----
    half8 wA0 = wp[0],    wA1 = wp[64],        wA2 = wp[128],        wA3 = wp[192];
    half8 wB0 = wp[1024], wB1 = wp[1024 + 64], wB2 = wp[1024 + 128], wB3 = wp[1024 + 192];
    f16 xA0 = xjA[0], xA1 = xjA[32], xA2 = xjA[4096], xA3 = xjA[4096 + 32];
    f16 xB0 = xjB[0], xB1 = xjB[32], xB2 = xjB[4096], xB3 = xjB[4096 + 32];

    // moving prefetch pointers (next targets: c=2 / c=3)
    const half8* wpA = wp + 2048;
    const half8* wpB = wp + 3072;
    const f16* xjpA = xjA + 128;
    const f16* xjpB = xjB + 128;

#pragma unroll 1
    for (int cc = 0; cc < 32; ++cc) {
      // ================= even c = 2*cc (A sets) =================
      {
        const half2v h0 = {xA0, xA0}, h1 = {xA1, xA1}, h2 = {xA2, xA2}, h3 = {xA3, xA3};
        __builtin_amdgcn_s_setprio(1);
#pragma unroll
        for (int kk = 0; kk < 4; ++kk) {
          const half8 w = (kk == 0) ? wA0 : (kk == 1) ? wA1 : (kk == 2) ? wA2 : wA3;
          acc[0] = MFMA(scale8(af[0][kk], h0), w, acc[0]);
          acc[1] = MFMA(scale8(af[1][kk], h1), w, acc[1]);
          acc[2] = MFMA(scale8(af[2][kk], h2), w, acc[2]);
          acc[3] = MFMA(scale8(af[3][kk], h3), w, acc[3]);
        }
        __builtin_amdgcn_s_setprio(0);
        if (cc < 31) {
          wA0 = wpA[0]; wA1 = wpA[64]; wA2 = wpA[128]; wA3 = wpA[192];
          xA0 = xjpA[0]; xA1 = xjpA[32]; xA2 = xjpA[4096]; xA3 = xjpA[4096 + 32];
          wpA += 2048; xjpA += 128;
        }
      }
      // ================= odd c = 2*cc+1 (B sets) =================
      {
        const half2v h0 = {xB0, xB0}, h1 = {xB1, xB1}, h2 = {xB2, xB2}, h3 = {xB3, xB3};
        __builtin_amdgcn_s_setprio(1);
#pragma unroll
        for (int kk = 0; kk < 4; ++kk) {
          const half8 w = (kk == 0) ? wB0 : (kk == 1) ? wB1 : (kk == 2) ? wB2 : wB3;
          acc[0] = MFMA(scale8(af[0][kk], h0), w, acc[0]);
          acc[1] = MFMA(scale8(af[1][kk], h1), w, acc[1]);
          acc[2] = MFMA(scale8(af[2][kk], h2), w, acc[2]);
          acc[3] = MFMA(scale8(af[3][kk], h3), w, acc[3]);
        }
        __builtin_amdgcn_s_setprio(0);
        if (cc < 31) {
          wB0 = wpB[0]; wB1 = wpB[64]; wB2 = wpB[128]; wB3 = wpB[192];
          xB0 = xjpB[0]; xB1 = xjpB[32]; xB2 = xjpB[4096]; xB3 = xjpB[4096 + 32];
          wpB += 2048; xjpB += 128;
        }
      }
    }

    // ---- epilogue: D layout col=lane&31 (f), row=(reg&3)+8*(reg>>2)+4*hi (d) ----
    const int fcol = wg * 32 + lr;
    float ps[4];
#pragma unroll
    for (int mf = 0; mf < 4; ++mf) {
      const int b = b0 + (mf >> 1);
      float* ob = out + (size_t)b * 8192 + (size_t)fcol * 64 + (mf & 1) * 32;
      const f32x16 v = acc[mf];
      float s = 0.f;
#pragma unroll
      for (int q = 0; q < 4; ++q) {
        f32x4 vv = { v[4 * q], v[4 * q + 1], v[4 * q + 2], v[4 * q + 3] };
        *(f32x4*)(ob + q * 8 + hi * 4) = vv;
        s += vv[0] + vv[1] + vv[2] + vv[3];
      }
      ps[mf] = s;
    }
    float pA = ps[0] + ps[1];   // batch b0
    float pB = ps[2] + ps[3];   // batch b0+1
    pA += __shfl_xor(pA, 32, 64);
    pB += __shfl_xor(pB, 32, 64);
    if (hi == 0) {
      pout[(size_t)b0 * 128 + fcol] = pA;
      pout[(size_t)(b0 + 1) * 128 + fcol] = pB;
    }
  }
}

extern "C" void kernel_launch(void* const* d_in, const int* in_sizes, int n_in,
                              void* d_out, int out_size, void* d_ws, size_t ws_size,
                              hipStream_t stream) {
  const float* xj = (const float*)d_in[0];   // (2048, 64, 64)
  const float* x0 = (const float*)d_in[1];   // (2048, 64, 64)
  const float* W  = (const float*)d_in[2];   // (128, 64, 64)
  float* out  = (float*)d_out;               // cin_out (2048,128,64), cin_p_out (2048,128)
  float* pout = out + (size_t)2048 * 128 * 64;
  f16* Wb = (f16*)d_ws;                      // 1 MiB fragment-major f16 W

  wscat_kernel<<<256, 256, 0, stream>>>(W, Wb);
  cin_kernel<<<512, 256, 0, stream>>>(xj, x0, Wb, out, pout);
}